// Round 12
// baseline (278.250 us; speedup 1.0000x reference)
//
#include <hip/hip_runtime.h>
#include <stdint.h>

// Problem constants (fixed by reference)
#define T_TOK 32768   // B*S = 8*4096
#define DIN   256
#define DHID  512
#define DOUT  256
#define NEXP  64
#define L1_SLOTS 4    // l1: 256-token chunks, 512-thr blocks
#define L2_SLOTS 8    // l2: 128-token chunks, 256-thr blocks (v11/v13 proven form)
#define ROUTER_BLOCKS 512
#define W1P_BLOCKS    512                  // (e, kt) slabs: 64 x 8
#define W2P_BLOCKS    1024                 // (e, kt) slabs: 64 x 16
#define XBF_BLOCKS    1024                 // x fp32 -> bf16 (8.39M elems = 1024*4096 uint)
#define RP_TOTAL (ROUTER_BLOCKS + W1P_BLOCKS + W2P_BLOCKS + XBF_BLOCKS)   // 3072
#define L1_BLOCKS (NEXP * 4 * L1_SLOTS)    // 1024
#define L2_BLOCKS (NEXP * 2 * L2_SLOTS)    // 1024
#define CMB_BLOCKS (T_TOK / 8)             // 4096 (8 tokens per 256-thr block)

typedef __attribute__((ext_vector_type(8))) short short8;   // 8 bf16 (4 VGPRs)
typedef __attribute__((ext_vector_type(4))) float f32x4;

// ---- workspace layout (bytes) ----  total ~146 MB
#define OFF_W1F   0u                       // 16 MiB bf16 fragment-ordered W1
#define OFF_W2F   16777216u                // 16 MiB bf16 fragment-ordered W2
#define OFF_BASE  33554432u
#define OFF_CNT   (OFF_BASE + 0u)          // 64 int
#define OFF_CUR   (OFF_BASE + 256u)        // 64 int
#define OFF_OFFS  (OFF_BASE + 512u)        // 65 int (token-slot prefix)
#define OFF_TOPKE (OFF_BASE + 2048u)       // 2T int
#define OFF_TOPKG (OFF_TOPKE + 262144u)    // 2T float
#define OFF_PERM  (OFF_TOPKG + 262144u)    // 2T int
#define OFF_PGATE (OFF_PERM + 262144u)     // 2T float (kept for layout compat)
#define OFF_ISLOT (OFF_PGATE + 262144u)    // 2T int: token t's two perm slots
#define OFF_XBF   (OFF_BASE + 2097152u)    // 16 MiB bf16 x [T][256]
#define OFF_H     (OFF_XBF + 16777216u)    // 64 MiB bf16 H [2T slots][512]
#define OFF_YP    (OFF_H + 67108864u)      // 32 MiB bf16 y [2T slots][256] (+b2, ungated)

__device__ __forceinline__ unsigned short f2bf(float f) {
    union { float f; unsigned u; } a; a.f = f;
    unsigned u = a.u;
    u += 0x7fffu + ((u >> 16) & 1u);   // RNE
    return (unsigned short)(u >> 16);
}
__device__ __forceinline__ unsigned pack2(float a, float b) {
    return (unsigned)f2bf(a) | ((unsigned)f2bf(b) << 16);
}
__device__ __forceinline__ float bf2f(unsigned short u) {
    union { unsigned u; float f; } a; a.u = (unsigned)u << 16; return a.f;
}

// async global->LDS DMA, 16B per lane. LDS dest MUST be wave-uniform; HW
// writes lane i's 16B at dest + i*16 (m104/m108). Global src is per-lane.
__device__ __forceinline__ void async_copy16(const uint4* g, uint4* l) {
    __builtin_amdgcn_global_load_lds(
        (const __attribute__((address_space(1))) unsigned int*)g,
        (__attribute__((address_space(3))) unsigned int*)l, 16, 0, 0);
}

// XCD-affinity decode (T1): blockIdx round-robins the 8 XCDs, so choose
// e ≡ bx (mod 8) -> all 16 blocks of expert e land on XCD e%8. Per-XCD
// resident weights: 8 experts x 512 KB (W1f) = 4 MB = one XCD L2.
__device__ __forceinline__ void xcd_decode(int bx, int& e, int& j) {
    int q = bx & 7, r = bx >> 3;
    j = r & 15;                 // 16 blocks per expert
    e = (r >> 4) * 8 + q;       // bijective over 1024
}

// ---------------------------------------------------------------------------
// Fused K1 v17: blocks [0,512) = router; [512,1024) = W1 prep; [1024,2048) =
// W2 prep; [2048,3072) = x->bf16.
// v16's weight prep did 8 scalar dword loads at 2 KB stride per 16 B of
// output (the measured dominator of router_prep's 56 us, VALUBusy 35%).
// v17: block = (e, 32-row k-slab); coalesced float4 slab load into LDS, then
// per-lane fragment gather from LDS (4-way quad conflict, off critical path)
// + coalesced uint4 stores. Prep blocks 8192 -> 1536; loads/byte / 8.
// B-fragment order: per 16(N)x32(K) tile, lane l holds
// B[k=kt*32+(l>>4)*8+j][n=nt*16+(l&15)], 64 lanes * 16B contiguous.
__global__ __launch_bounds__(256) void router_prep(const float* __restrict__ x,
                                                   const float* __restrict__ Wr,
                                                   const float* __restrict__ br,
                                                   const float* __restrict__ W1,
                                                   const float* __restrict__ W2,
                                                   uint4* __restrict__ W1f,
                                                   uint4* __restrict__ W2f,
                                                   int* __restrict__ topk_e,
                                                   float* __restrict__ topk_g,
                                                   int* __restrict__ cnt,
                                                   unsigned* __restrict__ xbf) {
    __shared__ float ldsf[32 * 516];   // 66,048 B; aliased per block role
    __shared__ int lcnt[NEXP];
    int tid = threadIdx.x, bx = blockIdx.x;

    if (bx >= ROUTER_BLOCKS + W1P_BLOCKS + W2P_BLOCKS) {
        // ---------------- x fp32 -> bf16 (row-major [T][256]) ----------------
        int blk = bx - (ROUTER_BLOCKS + W1P_BLOCKS + W2P_BLOCKS);
        const float2* xs = (const float2*)x;
#pragma unroll
        for (int k = 0; k < 16; ++k) {
            int o = blk * 4096 + k * 256 + tid;
            float2 v = xs[o];
            xbf[o] = pack2(v.x, v.y);
        }
        return;
    }
    if (bx >= ROUTER_BLOCKS + W1P_BLOCKS) {
        // ---------------- W2 prep: slab = 32k x 256n of W2[e] ----------------
        int blk = bx - (ROUTER_BLOCKS + W1P_BLOCKS);
        int e = blk >> 4, kt = blk & 15;
        float (*slab)[260] = (float(*)[260])ldsf;   // 33,280 B
        const float* src = W2 + (size_t)e * 131072 + (size_t)kt * 32 * DOUT;
#pragma unroll
        for (int m = 0; m < 8; ++m) {
            int idx = m * 256 + tid;
            int row = idx >> 6, c4 = idx & 63;      // 64 f4 per 256-col row
            *(float4*)&slab[row][c4 * 4] = *(const float4*)(src + row * DOUT + c4 * 4);
        }
        __syncthreads();
        int l = tid & 63, g = tid >> 6, quad = l >> 4, lr = l & 15;
#pragma unroll
        for (int rr = 0; rr < 4; ++rr) {
            int nt = rr * 4 + g;                    // 16 n-tiles
            float v[8];
#pragma unroll
            for (int j = 0; j < 8; ++j) v[j] = slab[quad * 8 + j][nt * 16 + lr];
            uint4 o;
            o.x = pack2(v[0], v[1]); o.y = pack2(v[2], v[3]);
            o.z = pack2(v[4], v[5]); o.w = pack2(v[6], v[7]);
            W2f[(size_t)(e * 256 + nt * 16 + kt) * 64 + l] = o;
        }
        return;
    }
    if (bx >= ROUTER_BLOCKS) {
        // ---------------- W1 prep: slab = 32k x 512n of W1[e] ----------------
        int blk = bx - ROUTER_BLOCKS;
        int e = blk >> 3, kt = blk & 7;
        float (*slab)[516] = (float(*)[516])ldsf;   // 66,048 B
        const float* src = W1 + (size_t)e * 131072 + (size_t)kt * 32 * DHID;
#pragma unroll
        for (int m = 0; m < 16; ++m) {
            int idx = m * 256 + tid;
            int row = idx >> 7, c4 = idx & 127;     // 128 f4 per 512-col row
            *(float4*)&slab[row][c4 * 4] = *(const float4*)(src + row * DHID + c4 * 4);
        }
        __syncthreads();
        int l = tid & 63, g = tid >> 6, quad = l >> 4, lr = l & 15;
#pragma unroll
        for (int rr = 0; rr < 8; ++rr) {
            int nt = rr * 4 + g;                    // 32 n-tiles
            float v[8];
#pragma unroll
            for (int j = 0; j < 8; ++j) v[j] = slab[quad * 8 + j][nt * 16 + lr];
            uint4 o;
            o.x = pack2(v[0], v[1]); o.y = pack2(v[2], v[3]);
            o.z = pack2(v[4], v[5]); o.w = pack2(v[6], v[7]);
            W1f[(size_t)(e * 256 + nt * 8 + kt) * 64 + l] = o;
        }
        return;
    }

    // ---------------- router (fp32 logits; bf16 would swap near-tie picks) --
    float (*xl)[68] = (float(*)[68])ldsf;                 // [64][68]
    float (*wt)[68] = (float(*)[68])(ldsf + 64 * 68);     // [64][68]
    if (tid < NEXP) lcnt[tid] = 0;
    int a = tid >> 4;        // expert group base
    int bcol = tid & 15;     // token group base
    int tok0 = bx * 64;
    float c[4][4];
#pragma unroll
    for (int i = 0; i < 4; ++i)
#pragma unroll
        for (int j = 0; j < 4; ++j) c[i][j] = 0.0f;

    for (int chunk = 0; chunk < 4; ++chunk) {
        int d0 = chunk * 64;
        {   // stage x[tok0..tok0+63][d0..d0+63]
            int tok = tid >> 2, off = (tid & 3) * 16;
            const float4* s = (const float4*)(x + (size_t)(tok0 + tok) * DIN + d0 + off);
            float4* d = (float4*)&xl[tok][off];
#pragma unroll
            for (int i = 0; i < 4; ++i) d[i] = s[i];
        }
        {   // stage Wr chunk transposed: wt[e][dd] = Wr[d0+dd][e]
            int dd = tid >> 2, ecol = (tid & 3) * 16;
            const float* s = Wr + (size_t)(d0 + dd) * NEXP + ecol;
#pragma unroll
            for (int j = 0; j < 16; ++j) wt[ecol + j][dd] = s[j];
        }
        __syncthreads();
#pragma unroll 4
        for (int d = 0; d < 64; d += 4) {
            float4 xv[4], wv[4];
#pragma unroll
            for (int i = 0; i < 4; ++i) xv[i] = *(const float4*)&xl[bcol + i * 16][d];
#pragma unroll
            for (int j = 0; j < 4; ++j) wv[j] = *(const float4*)&wt[a + j * 16][d];
#pragma unroll
            for (int i = 0; i < 4; ++i)
#pragma unroll
                for (int j = 0; j < 4; ++j) {
                    c[i][j] = fmaf(xv[i].x, wv[j].x, c[i][j]);
                    c[i][j] = fmaf(xv[i].y, wv[j].y, c[i][j]);
                    c[i][j] = fmaf(xv[i].z, wv[j].z, c[i][j]);
                    c[i][j] = fmaf(xv[i].w, wv[j].w, c[i][j]);
                }
        }
        __syncthreads();
    }
#pragma unroll
    for (int i = 0; i < 4; ++i)
#pragma unroll
        for (int j = 0; j < 4; ++j)
            xl[bcol + i * 16][a + j * 16] = c[i][j] + br[a + j * 16];
    __syncthreads();

    int w = tid >> 6, lane = tid & 63;
    for (int ti = 0; ti < 16; ++ti) {
        int tl = w * 16 + ti;
        float acc = xl[tl][lane];     // lane == expert
        float v = acc; int idx = lane;
#pragma unroll
        for (int m = 32; m; m >>= 1) {
            float ov = __shfl_xor(v, m); int oi = __shfl_xor(idx, m);
            if (ov > v || (ov == v && oi < idx)) { v = ov; idx = oi; }
        }
        int e0 = idx; float l0 = v;
        float v2 = (lane == e0) ? -3.4e38f : acc; int idx2 = lane;
#pragma unroll
        for (int m = 32; m; m >>= 1) {
            float ov = __shfl_xor(v2, m); int oi = __shfl_xor(idx2, m);
            if (ov > v2 || (ov == v2 && oi < idx2)) { v2 = ov; idx2 = oi; }
        }
        if (lane == 0) {
            int t = tok0 + tl;
            float ex = expf(v2 - l0);         // <= 1
            float g1 = ex / (1.0f + ex);
            topk_e[2 * t] = e0; topk_e[2 * t + 1] = idx2;
            topk_g[2 * t] = 1.0f - g1; topk_g[2 * t + 1] = g1;
            atomicAdd(&lcnt[e0], 1);
            atomicAdd(&lcnt[idx2], 1);
        }
    }
    __syncthreads();
    if (tid < NEXP) atomicAdd(&cnt[tid], lcnt[tid]);
}

// ---------------------------------------------------------------------------
// K2: scatter; wave 0 also scans cnt. Block 0 publishes offs (token-slot
// prefix). Also records islot[2t], islot[2t+1] = token t's perm slots, for
// the gather-combine kernel.
__global__ __launch_bounds__(256) void scatter_kernel(const int* __restrict__ topk_e,
                                                      const float* __restrict__ topk_g,
                                                      const int* __restrict__ cnt,
                                                      int* __restrict__ cursor,
                                                      int* __restrict__ perm,
                                                      int* __restrict__ islot,
                                                      int* __restrict__ offs_g) {
    __shared__ int lcnt[NEXP], lbase[NEXP], sOffs[NEXP];
    int tid = threadIdx.x;
    if (tid < NEXP) lcnt[tid] = 0;
    if (tid < 64) {   // wave 0
        int c = cnt[tid];
        int ic = c;
#pragma unroll
        for (int d = 1; d < 64; d <<= 1) {
            int vc = __shfl_up(ic, d);
            if (tid >= d) ic += vc;
        }
        sOffs[tid] = ic - c;
        if (blockIdx.x == 0) {
            offs_g[tid] = ic - c;
            if (tid == 63) offs_g[64] = ic;
        }
    }
    __syncthreads();
    int t = blockIdx.x * 256 + tid;
    int e0 = topk_e[2 * t], e1 = topk_e[2 * t + 1];
    int i0 = atomicAdd(&lcnt[e0], 1);
    int i1 = atomicAdd(&lcnt[e1], 1);
    __syncthreads();
    if (tid < NEXP) lbase[tid] = atomicAdd(&cursor[tid], lcnt[tid]);
    __syncthreads();
    int p0 = sOffs[e0] + lbase[e0] + i0;
    int p1 = sOffs[e1] + lbase[e1] + i1;
    perm[p0] = t;
    perm[p1] = t;
    islot[2 * t] = p0;
    islot[2 * t + 1] = p1;
}

// ---------------------------------------------------------------------------
// Expert FFN (v16 champion form, unchanged): expert-stationary with T1
// XCD-affinity swizzle; l1 512-thr one-64KB-strip; l2 256-thr two-k-halves;
// atomic-free yp epilogue + combine.
//
// expert_l1: block = (expert e, n-strip ns of DHID/128, slot). W1 strip
// (256k x 128n bf16 = 64 KB) staged in LDS ONCE; loop 256-token chunks.
// MFMA 16x16x32 bf16: A[m=lane&15][k=(lane>>4)*8+j]; C/D col=lane&15,
// row=(lane>>4)*4+reg.
__global__ __launch_bounds__(512, 4) void expert_l1(const unsigned short* __restrict__ xbf,
                                                    const uint4* __restrict__ W1f,
                                                    const float* __restrict__ b1,
                                                    const int* __restrict__ cnt,
                                                    const int* __restrict__ offs,
                                                    const int* __restrict__ perm,
                                                    unsigned short* __restrict__ H) {
    __shared__ uint4 Wlds[4096];   // 64 KB: [(i*8+kt)*64 + lane], i = nt within strip
    __shared__ int toks[256];
    __shared__ float b1s[128];

    int tid = threadIdx.x;
    int e, j;
    xcd_decode(blockIdx.x, e, j);
    int ns = j & 3, slot = j >> 2;
    int ne = cnt[e];
    if (slot * 256 >= ne) return;
    int base = offs[e];
    int w = tid >> 6, lane = tid & 63, quad = lane >> 4, lr = lane & 15;

    // stage W1 strip once: 64 contiguous fragment-tiles (nt in [ns*8, ns*8+8))
    // LDS dest wave-uniform (+w*64); HW adds lane*16B; src per-lane.
    const uint4* src = W1f + (size_t)(e * 256 + ns * 64) * 64;
#pragma unroll
    for (int r = 0; r < 8; ++r)
        async_copy16(src + r * 512 + w * 64 + lane, Wlds + r * 512 + w * 64);
    if (tid < 32)
        *(float4*)&b1s[tid * 4] =
            *(const float4*)(b1 + (size_t)e * DHID + ns * 128 + tid * 4);

    for (int mc = slot; mc * 256 < ne; mc += L1_SLOTS) {
        __syncthreads();   // prev chunk's toks reads done; 1st iter: DMA drain
        if (tid < 256) {
            int idx = mc * 256 + tid;
            toks[tid] = perm[base + (idx < ne ? idx : ne - 1)];
        }
        __syncthreads();   // toks visible

        // A-frags: wave w owns m-tiles 2w, 2w+1 (of 16); batch-issued
        short8 a[2][8];
#pragma unroll
        for (int mt = 0; mt < 2; ++mt) {
            const unsigned short* xr =
                xbf + (size_t)toks[(w * 2 + mt) * 16 + lr] * DIN + quad * 8;
#pragma unroll
            for (int kt = 0; kt < 8; ++kt) a[mt][kt] = *(const short8*)(xr + kt * 32);
        }

#pragma unroll
        for (int ntb = 0; ntb < 4; ++ntb) {
            f32x4 acc[2][2];   // [nt2][mt]
#pragma unroll
            for (int i = 0; i < 2; ++i)
#pragma unroll
                for (int m = 0; m < 2; ++m) acc[i][m] = (f32x4){0.f, 0.f, 0.f, 0.f};
#pragma unroll
            for (int kt = 0; kt < 8; ++kt) {
                short8 B0 = *(const short8*)&Wlds[((ntb * 2 + 0) * 8 + kt) * 64 + lane];
                short8 B1 = *(const short8*)&Wlds[((ntb * 2 + 1) * 8 + kt) * 64 + lane];
#pragma unroll
                for (int mt = 0; mt < 2; ++mt) {
                    acc[0][mt] = __builtin_amdgcn_mfma_f32_16x16x32_bf16(a[mt][kt], B0, acc[0][mt], 0, 0, 0);
                    acc[1][mt] = __builtin_amdgcn_mfma_f32_16x16x32_bf16(a[mt][kt], B1, acc[1][mt], 0, 0, 0);
                }
            }
#pragma unroll
            for (int nt2 = 0; nt2 < 2; ++nt2) {
                int nloc = ntb * 32 + nt2 * 16 + lr;
                float bias = b1s[nloc];
#pragma unroll
                for (int mt = 0; mt < 2; ++mt)
#pragma unroll
                    for (int r = 0; r < 4; ++r) {
                        int idx = mc * 256 + (w * 2 + mt) * 16 + quad * 4 + r;
                        if (idx < ne)
                            H[(size_t)(base + idx) * DHID + ns * 128 + nloc] =
                                f2bf(fmaxf(acc[nt2][mt][r] + bias, 0.0f));
                    }
            }
        }
    }
}

// ---------------------------------------------------------------------------
// expert_l2 (v13 proven form + swizzle): block = (expert, out-strip ns,
// slot), 256 thr; loops 128-token chunks. W2 strip staged per chunk in two
// 64 KB k-halves. Atomic-free: stores y+b2 (bf16) to perm-ordered yp.
__global__ __launch_bounds__(256, 2) void expert_l2(const unsigned short* __restrict__ H,
                                                    const uint4* __restrict__ W2f,
                                                    const float* __restrict__ b2,
                                                    const int* __restrict__ cnt,
                                                    const int* __restrict__ offs,
                                                    unsigned short* __restrict__ yp) {
    __shared__ uint4 Wlds[4096];   // 64 KB: [(nt*8 + ktl)*64 + lane]
    __shared__ float b2s[128];

    int tid = threadIdx.x;
    int e, j;
    xcd_decode(blockIdx.x, e, j);
    int ns = j & 1, slot = j >> 1;
    int ne = cnt[e];
    if (slot * 128 >= ne) return;
    int base = offs[e];
    int w = tid >> 6, lane = tid & 63, quad = lane >> 4, lr = lane & 15;

    if (tid < 32)
        *(float4*)&b2s[tid * 4] =
            *(const float4*)(b2 + (size_t)e * DOUT + ns * 128 + tid * 4);

    for (int mc = slot; mc * 128 < ne; mc += L2_SLOTS) {
        int row0 = mc * 128 + (w * 2 + 0) * 16 + lr;
        int row1 = mc * 128 + (w * 2 + 1) * 16 + lr;
        if (row0 >= ne) row0 = ne - 1;
        if (row1 >= ne) row1 = ne - 1;
        const unsigned short* h0 = H + (size_t)(base + row0) * DHID + quad * 8;
        const unsigned short* h1 = H + (size_t)(base + row1) * DHID + quad * 8;

        f32x4 acc[8][2];   // [nt][mt]
#pragma unroll
        for (int nt = 0; nt < 8; ++nt)
#pragma unroll
            for (int mt = 0; mt < 2; ++mt) acc[nt][mt] = (f32x4){0.f, 0.f, 0.f, 0.f};

#pragma unroll
        for (int kh = 0; kh < 2; ++kh) {
            __syncthreads();   // prev phase done reading Wlds
            // stage k-half: per nt, 512 contiguous uint4 (8 k-tiles)
#pragma unroll
            for (int nt = 0; nt < 8; ++nt) {
                const uint4* src = W2f + (size_t)(e * 256 + (ns * 8 + nt) * 16 + kh * 8) * 64;
                async_copy16(src + w * 64 + lane, Wlds + nt * 512 + w * 64);
                async_copy16(src + 256 + w * 64 + lane, Wlds + nt * 512 + 256 + w * 64);
            }
            __syncthreads();   // DMA drained

            // batch-issue all A-frags for this k-half
            short8 a[8][2];
#pragma unroll
            for (int kt = 0; kt < 8; ++kt) {
                a[kt][0] = *(const short8*)(h0 + kh * 256 + kt * 32);
                a[kt][1] = *(const short8*)(h1 + kh * 256 + kt * 32);
            }
#pragma unroll
            for (int kt = 0; kt < 8; ++kt) {
#pragma unroll
                for (int nt = 0; nt < 8; ++nt) {
                    short8 B = *(const short8*)&Wlds[(nt * 8 + kt) * 64 + lane];
                    acc[nt][0] = __builtin_amdgcn_mfma_f32_16x16x32_bf16(a[kt][0], B, acc[nt][0], 0, 0, 0);
                    acc[nt][1] = __builtin_amdgcn_mfma_f32_16x16x32_bf16(a[kt][1], B, acc[nt][1], 0, 0, 0);
                }
            }
        }

        // ---- epilogue: yp[slot] = y + b2 (bf16), plain stores ----
#pragma unroll
        for (int nt = 0; nt < 8; ++nt) {
            int nloc = nt * 16 + lr;
            float bias = b2s[nloc];
#pragma unroll
            for (int mt = 0; mt < 2; ++mt)
#pragma unroll
                for (int r = 0; r < 4; ++r) {
                    int crow = mc * 128 + (w * 2 + mt) * 16 + quad * 4 + r;
                    if (crow < ne)
                        yp[(size_t)(base + crow) * DOUT + ns * 128 + nloc] =
                            f2bf(acc[nt][mt][r] + bias);
                }
        }
    }
}

// ---------------------------------------------------------------------------
// combine: out[t] = g0 * yp[p0] + g1 * yp[p1]. Pure streaming gather; 8
// tokens per 256-thr block, 32 lanes x 8 cols per token.
__global__ __launch_bounds__(256) void combine_out(const unsigned short* __restrict__ yp,
                                                   const int* __restrict__ islot,
                                                   const float* __restrict__ topk_g,
                                                   float* __restrict__ out) {
    int tid = threadIdx.x;
    int tok = blockIdx.x * 8 + (tid >> 5);
    int cseg = (tid & 31) * 8;
    int p0 = islot[2 * tok], p1 = islot[2 * tok + 1];
    float g0 = topk_g[2 * tok], g1 = topk_g[2 * tok + 1];
    short8 v0 = *(const short8*)(yp + (size_t)p0 * DOUT + cseg);
    short8 v1 = *(const short8*)(yp + (size_t)p1 * DOUT + cseg);
    float4 o0, o1;
    o0.x = g0 * bf2f((unsigned short)v0[0]) + g1 * bf2f((unsigned short)v1[0]);
    o0.y = g0 * bf2f((unsigned short)v0[1]) + g1 * bf2f((unsigned short)v1[1]);
    o0.z = g0 * bf2f((unsigned short)v0[2]) + g1 * bf2f((unsigned short)v1[2]);
    o0.w = g0 * bf2f((unsigned short)v0[3]) + g1 * bf2f((unsigned short)v1[3]);
    o1.x = g0 * bf2f((unsigned short)v0[4]) + g1 * bf2f((unsigned short)v1[4]);
    o1.y = g0 * bf2f((unsigned short)v0[5]) + g1 * bf2f((unsigned short)v1[5]);
    o1.z = g0 * bf2f((unsigned short)v0[6]) + g1 * bf2f((unsigned short)v1[6]);
    o1.w = g0 * bf2f((unsigned short)v0[7]) + g1 * bf2f((unsigned short)v1[7]);
    float* d = out + (size_t)tok * DOUT + cseg;
    *(float4*)d = o0;
    *(float4*)(d + 4) = o1;
}

// ---------------------------------------------------------------------------
extern "C" void kernel_launch(void* const* d_in, const int* in_sizes, int n_in,
                              void* d_out, int out_size, void* d_ws, size_t ws_size,
                              hipStream_t stream) {
    (void)in_sizes; (void)n_in; (void)ws_size; (void)out_size;   // ws >= ~146 MB
    const float* x  = (const float*)d_in[0];
    const float* Wr = (const float*)d_in[1];
    const float* br = (const float*)d_in[2];
    const float* W1 = (const float*)d_in[3];
    const float* b1 = (const float*)d_in[4];
    const float* W2 = (const float*)d_in[5];
    const float* b2 = (const float*)d_in[6];
    float* out = (float*)d_out;
    char* ws = (char*)d_ws;

    uint4*    W1f    = (uint4*)(ws + OFF_W1F);
    uint4*    W2f    = (uint4*)(ws + OFF_W2F);
    int*      cnt    = (int*)(ws + OFF_CNT);
    int*      cursor = (int*)(ws + OFF_CUR);
    int*      offs   = (int*)(ws + OFF_OFFS);
    int*      topk_e = (int*)(ws + OFF_TOPKE);
    float*    topk_g = (float*)(ws + OFF_TOPKG);
    int*      perm   = (int*)(ws + OFF_PERM);
    int*      islot  = (int*)(ws + OFF_ISLOT);
    unsigned* xbf    = (unsigned*)(ws + OFF_XBF);
    unsigned short* Hbuf = (unsigned short*)(ws + OFF_H);
    unsigned short* ypb  = (unsigned short*)(ws + OFF_YP);

    hipMemsetAsync(ws + OFF_CNT, 0, 512, stream);   // cnt + cursor

    router_prep<<<RP_TOTAL, 256, 0, stream>>>(
        x, Wr, br, W1, W2, W1f, W2f, topk_e, topk_g, cnt, xbf);
    scatter_kernel<<<T_TOK / 256, 256, 0, stream>>>(topk_e, topk_g, cnt, cursor,
                                                    perm, islot, offs);
    expert_l1<<<L1_BLOCKS, 512, 0, stream>>>((const unsigned short*)xbf, W1f, b1,
                                             cnt, offs, perm, Hbuf);
    expert_l2<<<L2_BLOCKS, 256, 0, stream>>>(Hbuf, W2f, b2, cnt, offs, ypb);
    combine_out<<<CMB_BLOCKS, 256, 0, stream>>>(ypb, islot, topk_g, out);
}

// Round 14
// 263.251 us; speedup vs baseline: 1.0570x; 1.0570x over previous
//
#include <hip/hip_runtime.h>
#include <stdint.h>

// Problem constants (fixed by reference)
#define T_TOK 32768   // B*S = 8*4096
#define DIN   256
#define DHID  512
#define DOUT  256
#define NEXP  64
#define L1_SLOTS 4    // l1: 256-token chunks, 512-thr blocks
#define L2_SLOTS 8    // l2: 128-token chunks, 256-thr blocks (v11/v13 proven form)
#define ROUTER_BLOCKS (T_TOK / 64)         // 512
#define PREP_BLOCKS   8192
#define XBF_BLOCKS    1024                 // x fp32 -> bf16 (8.39M elems = 1024*4096 uint)
#define L1_BLOCKS (NEXP * 4 * L1_SLOTS)    // 1024
#define L2_BLOCKS (NEXP * 2 * L2_SLOTS)    // 1024
#define CMB_BLOCKS (T_TOK / 8)             // 4096 (8 tokens per 256-thr block)

typedef __attribute__((ext_vector_type(8))) short short8;   // 8 bf16 (4 VGPRs)
typedef __attribute__((ext_vector_type(4))) float f32x4;

// ---- workspace layout (bytes) ----  total ~146 MB
#define OFF_W1F   0u                       // 16 MiB bf16 fragment-ordered W1
#define OFF_W2F   16777216u                // 16 MiB bf16 fragment-ordered W2
#define OFF_BASE  33554432u
#define OFF_CNT   (OFF_BASE + 0u)          // 64 int
#define OFF_CUR   (OFF_BASE + 256u)        // 64 int
#define OFF_OFFS  (OFF_BASE + 512u)        // 65 int (token-slot prefix)
#define OFF_TOPKE (OFF_BASE + 2048u)       // 2T int
#define OFF_TOPKG (OFF_TOPKE + 262144u)    // 2T float
#define OFF_PERM  (OFF_TOPKG + 262144u)    // 2T int
#define OFF_PGATE (OFF_PERM + 262144u)     // 2T float (kept for layout compat)
#define OFF_ISLOT (OFF_PGATE + 262144u)    // 2T int: token t's two perm slots
#define OFF_XBF   (OFF_BASE + 2097152u)    // 16 MiB bf16 x [T][256]
#define OFF_H     (OFF_XBF + 16777216u)    // 64 MiB bf16 H [2T slots][512]
#define OFF_YP    (OFF_H + 67108864u)      // 32 MiB bf16 y [2T slots][256] (+b2, ungated)

__device__ __forceinline__ unsigned short f2bf(float f) {
    union { float f; unsigned u; } a; a.f = f;
    unsigned u = a.u;
    u += 0x7fffu + ((u >> 16) & 1u);   // RNE
    return (unsigned short)(u >> 16);
}
__device__ __forceinline__ unsigned pack2(float a, float b) {
    return (unsigned)f2bf(a) | ((unsigned)f2bf(b) << 16);
}
__device__ __forceinline__ float bf2f(unsigned short u) {
    union { unsigned u; float f; } a; a.u = (unsigned)u << 16; return a.f;
}

// async global->LDS DMA, 16B per lane. LDS dest MUST be wave-uniform; HW
// writes lane i's 16B at dest + i*16 (m104/m108). Global src is per-lane.
__device__ __forceinline__ void async_copy16(const uint4* g, uint4* l) {
    __builtin_amdgcn_global_load_lds(
        (const __attribute__((address_space(1))) unsigned int*)g,
        (__attribute__((address_space(3))) unsigned int*)l, 16, 0, 0);
}

// XCD-affinity decode (T1): blockIdx round-robins the 8 XCDs, so choose
// e ≡ bx (mod 8) -> all 16 blocks of expert e land on XCD e%8. Per-XCD
// resident weights: 8 experts x 512 KB (W1f) = 4 MB = one XCD L2. The
// per-dispatch weight re-stage stream (128 MB) becomes XCD-local L2 hits.
__device__ __forceinline__ void xcd_decode(int bx, int& e, int& j) {
    int q = bx & 7, r = bx >> 3;
    j = r & 15;                 // 16 blocks per expert
    e = (r >> 4) * 8 + q;       // bijective over 1024
}

// ---------------------------------------------------------------------------
// Fused K1: blocks [0,512) = router; [512, 8704) = weight prep (fp32 -> bf16
// MFMA B-fragment order); [8704, 9728) = x->bf16.
// B-fragment order: per 16(N)x32(K) tile, lane l holds
// B[k=kt*32+(l>>4)*8+j][n=nt*16+(l&15)], 64 lanes * 16B contiguous.
__global__ __launch_bounds__(256) void router_prep(const float* __restrict__ x,
                                                   const float* __restrict__ Wr,
                                                   const float* __restrict__ br,
                                                   const float* __restrict__ W1,
                                                   const float* __restrict__ W2,
                                                   uint4* __restrict__ W1f,
                                                   uint4* __restrict__ W2f,
                                                   int* __restrict__ topk_e,
                                                   float* __restrict__ topk_g,
                                                   int* __restrict__ cnt,
                                                   unsigned* __restrict__ xbf) {
    __shared__ float xl[64][68];   // x chunk [tok][d], later logits [tok][e]
    __shared__ float wt[64][68];   // Wr transposed chunk [e][d]
    __shared__ int lcnt[NEXP];
    int tid = threadIdx.x;

    if (blockIdx.x >= ROUTER_BLOCKS + PREP_BLOCKS) {
        // ---------------- x fp32 -> bf16 (row-major [T][256]) ----------------
        int blk = blockIdx.x - (ROUTER_BLOCKS + PREP_BLOCKS);
        const float2* xs = (const float2*)x;
#pragma unroll
        for (int k = 0; k < 16; ++k) {
            int o = blk * 4096 + k * 256 + tid;
            float2 v = xs[o];
            xbf[o] = pack2(v.x, v.y);
        }
        return;
    }
    if (blockIdx.x >= ROUTER_BLOCKS) {
        // ---------------- weight prep ----------------
        int g = (blockIdx.x - ROUTER_BLOCKS) * 256 + tid;   // 0 .. 2*2^20-1
        int isW2 = g >> 20;
        int gg = g & ((1 << 20) - 1);
        int l = gg & 63;
        int t = gg >> 6;            // tile id over all experts
        int e = t >> 8;
        int rem = t & 255;
        int quad = l >> 4, lr = l & 15;
        float v[8];
        if (!isW2) {
            int nt = rem >> 3, kt = rem & 7;          // 32 n-tiles, 8 k-tiles
            int kb = kt * 32 + quad * 8;
            int n = nt * 16 + lr;
            const float* s = W1 + (size_t)e * DIN * DHID + n;
#pragma unroll
            for (int j = 0; j < 8; ++j) v[j] = s[(size_t)(kb + j) * DHID];
        } else {
            int nt = rem >> 4, kt = rem & 15;         // 16 n-tiles, 16 k-tiles
            int kb = kt * 32 + quad * 8;
            int n = nt * 16 + lr;
            const float* s = W2 + (size_t)e * DHID * DOUT + n;
#pragma unroll
            for (int j = 0; j < 8; ++j) v[j] = s[(size_t)(kb + j) * DOUT];
        }
        uint4 o;
        o.x = pack2(v[0], v[1]); o.y = pack2(v[2], v[3]);
        o.z = pack2(v[4], v[5]); o.w = pack2(v[6], v[7]);
        (isW2 ? W2f : W1f)[gg] = o;
        return;
    }

    // ---------------- router (fp32 logits; bf16 would swap near-tie picks) --
    if (tid < NEXP) lcnt[tid] = 0;
    int a = tid >> 4;        // expert group base
    int bcol = tid & 15;     // token group base
    int tok0 = blockIdx.x * 64;
    float c[4][4];
#pragma unroll
    for (int i = 0; i < 4; ++i)
#pragma unroll
        for (int j = 0; j < 4; ++j) c[i][j] = 0.0f;

    for (int chunk = 0; chunk < 4; ++chunk) {
        int d0 = chunk * 64;
        {   // stage x[tok0..tok0+63][d0..d0+63]
            int tok = tid >> 2, off = (tid & 3) * 16;
            const float4* s = (const float4*)(x + (size_t)(tok0 + tok) * DIN + d0 + off);
            float4* d = (float4*)&xl[tok][off];
#pragma unroll
            for (int i = 0; i < 4; ++i) d[i] = s[i];
        }
        {   // stage Wr chunk transposed: wt[e][dd] = Wr[d0+dd][e]
            int dd = tid >> 2, ecol = (tid & 3) * 16;
            const float* s = Wr + (size_t)(d0 + dd) * NEXP + ecol;
#pragma unroll
            for (int j = 0; j < 16; ++j) wt[ecol + j][dd] = s[j];
        }
        __syncthreads();
#pragma unroll 4
        for (int d = 0; d < 64; d += 4) {
            float4 xv[4], wv[4];
#pragma unroll
            for (int i = 0; i < 4; ++i) xv[i] = *(const float4*)&xl[bcol + i * 16][d];
#pragma unroll
            for (int j = 0; j < 4; ++j) wv[j] = *(const float4*)&wt[a + j * 16][d];
#pragma unroll
            for (int i = 0; i < 4; ++i)
#pragma unroll
                for (int j = 0; j < 4; ++j) {
                    c[i][j] = fmaf(xv[i].x, wv[j].x, c[i][j]);
                    c[i][j] = fmaf(xv[i].y, wv[j].y, c[i][j]);
                    c[i][j] = fmaf(xv[i].z, wv[j].z, c[i][j]);
                    c[i][j] = fmaf(xv[i].w, wv[j].w, c[i][j]);
                }
        }
        __syncthreads();
    }
#pragma unroll
    for (int i = 0; i < 4; ++i)
#pragma unroll
        for (int j = 0; j < 4; ++j)
            xl[bcol + i * 16][a + j * 16] = c[i][j] + br[a + j * 16];
    __syncthreads();

    int w = tid >> 6, lane = tid & 63;
    for (int ti = 0; ti < 16; ++ti) {
        int tl = w * 16 + ti;
        float acc = xl[tl][lane];     // lane == expert
        float v = acc; int idx = lane;
#pragma unroll
        for (int m = 32; m; m >>= 1) {
            float ov = __shfl_xor(v, m); int oi = __shfl_xor(idx, m);
            if (ov > v || (ov == v && oi < idx)) { v = ov; idx = oi; }
        }
        int e0 = idx; float l0 = v;
        float v2 = (lane == e0) ? -3.4e38f : acc; int idx2 = lane;
#pragma unroll
        for (int m = 32; m; m >>= 1) {
            float ov = __shfl_xor(v2, m); int oi = __shfl_xor(idx2, m);
            if (ov > v2 || (ov == v2 && oi < idx2)) { v2 = ov; idx2 = oi; }
        }
        if (lane == 0) {
            int t = tok0 + tl;
            float ex = expf(v2 - l0);         // <= 1
            float g1 = ex / (1.0f + ex);
            topk_e[2 * t] = e0; topk_e[2 * t + 1] = idx2;
            topk_g[2 * t] = 1.0f - g1; topk_g[2 * t + 1] = g1;
            atomicAdd(&lcnt[e0], 1);
            atomicAdd(&lcnt[idx2], 1);
        }
    }
    __syncthreads();
    if (tid < NEXP) atomicAdd(&cnt[tid], lcnt[tid]);
}

// ---------------------------------------------------------------------------
// K2: scatter; wave 0 also scans cnt. Block 0 publishes offs (token-slot
// prefix). Also records islot[2t], islot[2t+1] = token t's perm slots, for
// the gather-combine kernel.
__global__ __launch_bounds__(256) void scatter_kernel(const int* __restrict__ topk_e,
                                                      const float* __restrict__ topk_g,
                                                      const int* __restrict__ cnt,
                                                      int* __restrict__ cursor,
                                                      int* __restrict__ perm,
                                                      int* __restrict__ islot,
                                                      int* __restrict__ offs_g) {
    __shared__ int lcnt[NEXP], lbase[NEXP], sOffs[NEXP];
    int tid = threadIdx.x;
    if (tid < NEXP) lcnt[tid] = 0;
    if (tid < 64) {   // wave 0
        int c = cnt[tid];
        int ic = c;
#pragma unroll
        for (int d = 1; d < 64; d <<= 1) {
            int vc = __shfl_up(ic, d);
            if (tid >= d) ic += vc;
        }
        sOffs[tid] = ic - c;
        if (blockIdx.x == 0) {
            offs_g[tid] = ic - c;
            if (tid == 63) offs_g[64] = ic;
        }
    }
    __syncthreads();
    int t = blockIdx.x * 256 + tid;
    int e0 = topk_e[2 * t], e1 = topk_e[2 * t + 1];
    int i0 = atomicAdd(&lcnt[e0], 1);
    int i1 = atomicAdd(&lcnt[e1], 1);
    __syncthreads();
    if (tid < NEXP) lbase[tid] = atomicAdd(&cursor[tid], lcnt[tid]);
    __syncthreads();
    int p0 = sOffs[e0] + lbase[e0] + i0;
    int p1 = sOffs[e1] + lbase[e1] + i1;
    perm[p0] = t;
    perm[p1] = t;
    islot[2 * t] = p0;
    islot[2 * t + 1] = p1;
}

// ---------------------------------------------------------------------------
// Expert FFN v16 = v13 (282 us champion) + T1 XCD-affinity swizzle on the
// l1/l2 grids. v13's l1/l2 put an expert's blocks on 8 different XCDs, so
// the 128 MB weight re-stage stream missed every XCD-local L2. Now expert
// e's blocks all land on XCD e%8: per-XCD weights = 8 x 512 KB (W1f) = 4 MB
// (exactly one L2) / 8 x 256 KB (W2f) = 2 MB; l2's ns=0/1 blocks of one
// expert also share H rows through the same L2.
//
// expert_l1: block = (expert e, n-strip ns of DHID/128, slot). W1 strip
// (256k x 128n bf16 = 64 KB) staged in LDS ONCE; loop 256-token chunks.
// MFMA 16x16x32 bf16: A[m=lane&15][k=(lane>>4)*8+j]; C/D col=lane&15,
// row=(lane>>4)*4+reg.
__global__ __launch_bounds__(512, 4) void expert_l1(const unsigned short* __restrict__ xbf,
                                                    const uint4* __restrict__ W1f,
                                                    const float* __restrict__ b1,
                                                    const int* __restrict__ cnt,
                                                    const int* __restrict__ offs,
                                                    const int* __restrict__ perm,
                                                    unsigned short* __restrict__ H) {
    __shared__ uint4 Wlds[4096];   // 64 KB: [(i*8+kt)*64 + lane], i = nt within strip
    __shared__ int toks[256];
    __shared__ float b1s[128];

    int tid = threadIdx.x;
    int e, j;
    xcd_decode(blockIdx.x, e, j);
    int ns = j & 3, slot = j >> 2;
    int ne = cnt[e];
    if (slot * 256 >= ne) return;
    int base = offs[e];
    int w = tid >> 6, lane = tid & 63, quad = lane >> 4, lr = lane & 15;

    // stage W1 strip once: 64 contiguous fragment-tiles (nt in [ns*8, ns*8+8))
    // LDS dest wave-uniform (+w*64); HW adds lane*16B; src per-lane.
    const uint4* src = W1f + (size_t)(e * 256 + ns * 64) * 64;
#pragma unroll
    for (int r = 0; r < 8; ++r)
        async_copy16(src + r * 512 + w * 64 + lane, Wlds + r * 512 + w * 64);
    if (tid < 32)
        *(float4*)&b1s[tid * 4] =
            *(const float4*)(b1 + (size_t)e * DHID + ns * 128 + tid * 4);

    for (int mc = slot; mc * 256 < ne; mc += L1_SLOTS) {
        __syncthreads();   // prev chunk's toks reads done; 1st iter: DMA drain
        if (tid < 256) {
            int idx = mc * 256 + tid;
            toks[tid] = perm[base + (idx < ne ? idx : ne - 1)];
        }
        __syncthreads();   // toks visible

        // A-frags: wave w owns m-tiles 2w, 2w+1 (of 16); batch-issued
        short8 a[2][8];
#pragma unroll
        for (int mt = 0; mt < 2; ++mt) {
            const unsigned short* xr =
                xbf + (size_t)toks[(w * 2 + mt) * 16 + lr] * DIN + quad * 8;
#pragma unroll
            for (int kt = 0; kt < 8; ++kt) a[mt][kt] = *(const short8*)(xr + kt * 32);
        }

#pragma unroll
        for (int ntb = 0; ntb < 4; ++ntb) {
            f32x4 acc[2][2];   // [nt2][mt]
#pragma unroll
            for (int i = 0; i < 2; ++i)
#pragma unroll
                for (int m = 0; m < 2; ++m) acc[i][m] = (f32x4){0.f, 0.f, 0.f, 0.f};
#pragma unroll
            for (int kt = 0; kt < 8; ++kt) {
                short8 B0 = *(const short8*)&Wlds[((ntb * 2 + 0) * 8 + kt) * 64 + lane];
                short8 B1 = *(const short8*)&Wlds[((ntb * 2 + 1) * 8 + kt) * 64 + lane];
#pragma unroll
                for (int mt = 0; mt < 2; ++mt) {
                    acc[0][mt] = __builtin_amdgcn_mfma_f32_16x16x32_bf16(a[mt][kt], B0, acc[0][mt], 0, 0, 0);
                    acc[1][mt] = __builtin_amdgcn_mfma_f32_16x16x32_bf16(a[mt][kt], B1, acc[1][mt], 0, 0, 0);
                }
            }
#pragma unroll
            for (int nt2 = 0; nt2 < 2; ++nt2) {
                int nloc = ntb * 32 + nt2 * 16 + lr;
                float bias = b1s[nloc];
#pragma unroll
                for (int mt = 0; mt < 2; ++mt)
#pragma unroll
                    for (int r = 0; r < 4; ++r) {
                        int idx = mc * 256 + (w * 2 + mt) * 16 + quad * 4 + r;
                        if (idx < ne)
                            H[(size_t)(base + idx) * DHID + ns * 128 + nloc] =
                                f2bf(fmaxf(acc[nt2][mt][r] + bias, 0.0f));
                    }
            }
        }
    }
}

// ---------------------------------------------------------------------------
// expert_l2 (v13 proven form + swizzle): block = (expert, out-strip ns,
// slot), 256 thr; loops 128-token chunks. W2 strip staged per chunk in two
// 64 KB k-halves. Atomic-free: stores y+b2 (bf16) to perm-ordered yp.
__global__ __launch_bounds__(256, 2) void expert_l2(const unsigned short* __restrict__ H,
                                                    const uint4* __restrict__ W2f,
                                                    const float* __restrict__ b2,
                                                    const int* __restrict__ cnt,
                                                    const int* __restrict__ offs,
                                                    unsigned short* __restrict__ yp) {
    __shared__ uint4 Wlds[4096];   // 64 KB: [(nt*8 + ktl)*64 + lane]
    __shared__ float b2s[128];

    int tid = threadIdx.x;
    int e, j;
    xcd_decode(blockIdx.x, e, j);
    int ns = j & 1, slot = j >> 1;
    int ne = cnt[e];
    if (slot * 128 >= ne) return;
    int base = offs[e];
    int w = tid >> 6, lane = tid & 63, quad = lane >> 4, lr = lane & 15;

    if (tid < 32)
        *(float4*)&b2s[tid * 4] =
            *(const float4*)(b2 + (size_t)e * DOUT + ns * 128 + tid * 4);

    for (int mc = slot; mc * 128 < ne; mc += L2_SLOTS) {
        int row0 = mc * 128 + (w * 2 + 0) * 16 + lr;
        int row1 = mc * 128 + (w * 2 + 1) * 16 + lr;
        if (row0 >= ne) row0 = ne - 1;
        if (row1 >= ne) row1 = ne - 1;
        const unsigned short* h0 = H + (size_t)(base + row0) * DHID + quad * 8;
        const unsigned short* h1 = H + (size_t)(base + row1) * DHID + quad * 8;

        f32x4 acc[8][2];   // [nt][mt]
#pragma unroll
        for (int nt = 0; nt < 8; ++nt)
#pragma unroll
            for (int mt = 0; mt < 2; ++mt) acc[nt][mt] = (f32x4){0.f, 0.f, 0.f, 0.f};

#pragma unroll
        for (int kh = 0; kh < 2; ++kh) {
            __syncthreads();   // prev phase done reading Wlds
            // stage k-half: per nt, 512 contiguous uint4 (8 k-tiles)
#pragma unroll
            for (int nt = 0; nt < 8; ++nt) {
                const uint4* src = W2f + (size_t)(e * 256 + (ns * 8 + nt) * 16 + kh * 8) * 64;
                async_copy16(src + w * 64 + lane, Wlds + nt * 512 + w * 64);
                async_copy16(src + 256 + w * 64 + lane, Wlds + nt * 512 + 256 + w * 64);
            }
            __syncthreads();   // DMA drained

            // batch-issue all A-frags for this k-half
            short8 a[8][2];
#pragma unroll
            for (int kt = 0; kt < 8; ++kt) {
                a[kt][0] = *(const short8*)(h0 + kh * 256 + kt * 32);
                a[kt][1] = *(const short8*)(h1 + kh * 256 + kt * 32);
            }
#pragma unroll
            for (int kt = 0; kt < 8; ++kt) {
#pragma unroll
                for (int nt = 0; nt < 8; ++nt) {
                    short8 B = *(const short8*)&Wlds[(nt * 8 + kt) * 64 + lane];
                    acc[nt][0] = __builtin_amdgcn_mfma_f32_16x16x32_bf16(a[kt][0], B, acc[nt][0], 0, 0, 0);
                    acc[nt][1] = __builtin_amdgcn_mfma_f32_16x16x32_bf16(a[kt][1], B, acc[nt][1], 0, 0, 0);
                }
            }
        }

        // ---- epilogue: yp[slot] = y + b2 (bf16), plain stores ----
#pragma unroll
        for (int nt = 0; nt < 8; ++nt) {
            int nloc = nt * 16 + lr;
            float bias = b2s[nloc];
#pragma unroll
            for (int mt = 0; mt < 2; ++mt)
#pragma unroll
                for (int r = 0; r < 4; ++r) {
                    int crow = mc * 128 + (w * 2 + mt) * 16 + quad * 4 + r;
                    if (crow < ne)
                        yp[(size_t)(base + crow) * DOUT + ns * 128 + nloc] =
                            f2bf(acc[nt][mt][r] + bias);
                }
        }
    }
}

// ---------------------------------------------------------------------------
// combine: out[t] = g0 * yp[p0] + g1 * yp[p1]. Pure streaming gather; 8
// tokens per 256-thr block, 32 lanes x 8 cols per token.
__global__ __launch_bounds__(256) void combine_out(const unsigned short* __restrict__ yp,
                                                   const int* __restrict__ islot,
                                                   const float* __restrict__ topk_g,
                                                   float* __restrict__ out) {
    int tid = threadIdx.x;
    int tok = blockIdx.x * 8 + (tid >> 5);
    int cseg = (tid & 31) * 8;
    int p0 = islot[2 * tok], p1 = islot[2 * tok + 1];
    float g0 = topk_g[2 * tok], g1 = topk_g[2 * tok + 1];
    short8 v0 = *(const short8*)(yp + (size_t)p0 * DOUT + cseg);
    short8 v1 = *(const short8*)(yp + (size_t)p1 * DOUT + cseg);
    float4 o0, o1;
    o0.x = g0 * bf2f((unsigned short)v0[0]) + g1 * bf2f((unsigned short)v1[0]);
    o0.y = g0 * bf2f((unsigned short)v0[1]) + g1 * bf2f((unsigned short)v1[1]);
    o0.z = g0 * bf2f((unsigned short)v0[2]) + g1 * bf2f((unsigned short)v1[2]);
    o0.w = g0 * bf2f((unsigned short)v0[3]) + g1 * bf2f((unsigned short)v1[3]);
    o1.x = g0 * bf2f((unsigned short)v0[4]) + g1 * bf2f((unsigned short)v1[4]);
    o1.y = g0 * bf2f((unsigned short)v0[5]) + g1 * bf2f((unsigned short)v1[5]);
    o1.z = g0 * bf2f((unsigned short)v0[6]) + g1 * bf2f((unsigned short)v1[6]);
    o1.w = g0 * bf2f((unsigned short)v0[7]) + g1 * bf2f((unsigned short)v1[7]);
    float* d = out + (size_t)tok * DOUT + cseg;
    *(float4*)d = o0;
    *(float4*)(d + 4) = o1;
}

// ---------------------------------------------------------------------------
extern "C" void kernel_launch(void* const* d_in, const int* in_sizes, int n_in,
                              void* d_out, int out_size, void* d_ws, size_t ws_size,
                              hipStream_t stream) {
    (void)in_sizes; (void)n_in; (void)ws_size; (void)out_size;   // ws >= ~146 MB
    const float* x  = (const float*)d_in[0];
    const float* Wr = (const float*)d_in[1];
    const float* br = (const float*)d_in[2];
    const float* W1 = (const float*)d_in[3];
    const float* b1 = (const float*)d_in[4];
    const float* W2 = (const float*)d_in[5];
    const float* b2 = (const float*)d_in[6];
    float* out = (float*)d_out;
    char* ws = (char*)d_ws;

    uint4*    W1f    = (uint4*)(ws + OFF_W1F);
    uint4*    W2f    = (uint4*)(ws + OFF_W2F);
    int*      cnt    = (int*)(ws + OFF_CNT);
    int*      cursor = (int*)(ws + OFF_CUR);
    int*      offs   = (int*)(ws + OFF_OFFS);
    int*      topk_e = (int*)(ws + OFF_TOPKE);
    float*    topk_g = (float*)(ws + OFF_TOPKG);
    int*      perm   = (int*)(ws + OFF_PERM);
    int*      islot  = (int*)(ws + OFF_ISLOT);
    unsigned* xbf    = (unsigned*)(ws + OFF_XBF);
    unsigned short* Hbuf = (unsigned short*)(ws + OFF_H);
    unsigned short* ypb  = (unsigned short*)(ws + OFF_YP);

    hipMemsetAsync(ws + OFF_CNT, 0, 512, stream);   // cnt + cursor

    router_prep<<<ROUTER_BLOCKS + PREP_BLOCKS + XBF_BLOCKS, 256, 0, stream>>>(
        x, Wr, br, W1, W2, W1f, W2f, topk_e, topk_g, cnt, xbf);
    scatter_kernel<<<T_TOK / 256, 256, 0, stream>>>(topk_e, topk_g, cnt, cursor,
                                                    perm, islot, offs);
    expert_l1<<<L1_BLOCKS, 512, 0, stream>>>((const unsigned short*)xbf, W1f, b1,
                                             cnt, offs, perm, Hbuf);
    expert_l2<<<L2_BLOCKS, 256, 0, stream>>>(Hbuf, W2f, b2, cnt, offs, ypb);
    combine_out<<<CMB_BLOCKS, 256, 0, stream>>>(ypb, islot, topk_g, out);
}

// Round 15
// 262.814 us; speedup vs baseline: 1.0587x; 1.0017x over previous
//
#include <hip/hip_runtime.h>
#include <stdint.h>

// Problem constants (fixed by reference)
#define T_TOK 32768   // B*S = 8*4096
#define DIN   256
#define DHID  512
#define DOUT  256
#define NEXP  64
#define L1_SLOTS 4    // l1: 256-token chunks, 512-thr blocks
#define L2_SLOTS 8    // l2: 128-token chunks, 256-thr blocks (v11/v13 proven form)
#define ROUTER_BLOCKS 512
#define W1P_BLOCKS    4096                 // strided W1 prep (v16-verified path)
#define W2P_BLOCKS    1024                 // coalesced W2 slab prep (v17-verified path)
#define XBF_BLOCKS    1024                 // x fp32 -> bf16 (8.39M elems = 1024*4096 uint)
#define RP_TOTAL (ROUTER_BLOCKS + W1P_BLOCKS + W2P_BLOCKS + XBF_BLOCKS)   // 6656
#define L1_BLOCKS (NEXP * 4 * L1_SLOTS)    // 1024
#define L2_BLOCKS (NEXP * 2 * L2_SLOTS)    // 1024
#define CMB_BLOCKS (T_TOK / 8)             // 4096 (8 tokens per 256-thr block)

typedef __attribute__((ext_vector_type(8))) short short8;   // 8 bf16 (4 VGPRs)
typedef __attribute__((ext_vector_type(4))) float f32x4;

// ---- workspace layout (bytes) ----  total ~146 MB
#define OFF_W1F   0u                       // 16 MiB bf16 fragment-ordered W1
#define OFF_W2F   16777216u                // 16 MiB bf16 fragment-ordered W2
#define OFF_BASE  33554432u
#define OFF_CNT   (OFF_BASE + 0u)          // 64 int
#define OFF_CUR   (OFF_BASE + 256u)        // 64 int
#define OFF_OFFS  (OFF_BASE + 512u)        // 65 int (token-slot prefix)
#define OFF_TOPKE (OFF_BASE + 2048u)       // 2T int
#define OFF_TOPKG (OFF_TOPKE + 262144u)    // 2T float
#define OFF_PERM  (OFF_TOPKG + 262144u)    // 2T int
#define OFF_PGATE (OFF_PERM + 262144u)     // 2T float (kept for layout compat)
#define OFF_ISLOT (OFF_PGATE + 262144u)    // 2T int: token t's two perm slots
#define OFF_XBF   (OFF_BASE + 2097152u)    // 16 MiB bf16 x [T][256]
#define OFF_H     (OFF_XBF + 16777216u)    // 64 MiB bf16 H [2T slots][512]
#define OFF_YP    (OFF_H + 67108864u)      // 32 MiB bf16 y [2T slots][256] (+b2, ungated)

__device__ __forceinline__ unsigned short f2bf(float f) {
    union { float f; unsigned u; } a; a.f = f;
    unsigned u = a.u;
    u += 0x7fffu + ((u >> 16) & 1u);   // RNE
    return (unsigned short)(u >> 16);
}
__device__ __forceinline__ unsigned pack2(float a, float b) {
    return (unsigned)f2bf(a) | ((unsigned)f2bf(b) << 16);
}
__device__ __forceinline__ float bf2f(unsigned short u) {
    union { unsigned u; float f; } a; a.u = (unsigned)u << 16; return a.f;
}

// async global->LDS DMA, 16B per lane. LDS dest MUST be wave-uniform; HW
// writes lane i's 16B at dest + i*16 (m104/m108). Global src is per-lane.
__device__ __forceinline__ void async_copy16(const uint4* g, uint4* l) {
    __builtin_amdgcn_global_load_lds(
        (const __attribute__((address_space(1))) unsigned int*)g,
        (__attribute__((address_space(3))) unsigned int*)l, 16, 0, 0);
}

// XCD-affinity decode (T1): blockIdx round-robins the 8 XCDs, so choose
// e ≡ bx (mod 8) -> all 16 blocks of expert e land on XCD e%8. Per-XCD
// resident weights: 8 experts x 512 KB (W1f) = 4 MB = one XCD L2. The
// per-dispatch weight re-stage stream (128 MB) becomes XCD-local L2 hits.
__device__ __forceinline__ void xcd_decode(int bx, int& e, int& j) {
    int q = bx & 7, r = bx >> 3;
    j = r & 15;                 // 16 blocks per expert
    e = (r >> 4) * 8 + q;       // bijective over 1024
}

// ---------------------------------------------------------------------------
// Fused K1 v19: blocks [0,512) = router (v17-verified ldsf-aliased form);
// [512,4608) = W1 prep (v16-verified strided form); [4608,5632) = W2 prep
// (v17-verified coalesced slab form); [5632,6656) = x->bf16 (v16 form).
// Hedged composition: every role has individually passed the harness; the
// only never-verified code (v18's W1 half-slab) is excluded.
// B-fragment order: per 16(N)x32(K) tile, lane l holds
// B[k=kt*32+(l>>4)*8+j][n=nt*16+(l&15)], 64 lanes * 16B contiguous.
__global__ __launch_bounds__(256) void router_prep(const float* __restrict__ x,
                                                   const float* __restrict__ Wr,
                                                   const float* __restrict__ br,
                                                   const float* __restrict__ W1,
                                                   const float* __restrict__ W2,
                                                   uint4* __restrict__ W1f,
                                                   uint4* __restrict__ W2f,
                                                   int* __restrict__ topk_e,
                                                   float* __restrict__ topk_g,
                                                   int* __restrict__ cnt,
                                                   unsigned* __restrict__ xbf) {
    __shared__ float ldsf[8704];   // 34,816 B; aliased per block role
    __shared__ int lcnt[NEXP];
    int tid = threadIdx.x, bx = blockIdx.x;

    if (bx >= ROUTER_BLOCKS + W1P_BLOCKS + W2P_BLOCKS) {
        // ---------------- x fp32 -> bf16 (row-major [T][256]) ----------------
        int blk = bx - (ROUTER_BLOCKS + W1P_BLOCKS + W2P_BLOCKS);
        const float2* xs = (const float2*)x;
#pragma unroll
        for (int k = 0; k < 16; ++k) {
            int o = blk * 4096 + k * 256 + tid;
            float2 v = xs[o];
            xbf[o] = pack2(v.x, v.y);
        }
        return;
    }
    if (bx >= ROUTER_BLOCKS + W1P_BLOCKS) {
        // ------ W2 prep (v17-verified): slab = 32k x 256n of W2[e] ----------
        int blk = bx - (ROUTER_BLOCKS + W1P_BLOCKS);
        int e = blk >> 4, kt = blk & 15;
        float (*slab)[260] = (float(*)[260])ldsf;   // 33,280 B
        const float* src = W2 + (size_t)e * 131072 + (size_t)kt * 32 * DOUT;
#pragma unroll
        for (int m = 0; m < 8; ++m) {
            int idx = m * 256 + tid;
            int row = idx >> 6, c4 = idx & 63;      // 64 f4 per 256-col row
            *(float4*)&slab[row][c4 * 4] = *(const float4*)(src + row * DOUT + c4 * 4);
        }
        __syncthreads();
        int l = tid & 63, g = tid >> 6, quad = l >> 4, lr = l & 15;
#pragma unroll
        for (int rr = 0; rr < 4; ++rr) {
            int nt = rr * 4 + g;                    // 16 n-tiles
            float v[8];
#pragma unroll
            for (int j = 0; j < 8; ++j) v[j] = slab[quad * 8 + j][nt * 16 + lr];
            uint4 o;
            o.x = pack2(v[0], v[1]); o.y = pack2(v[2], v[3]);
            o.z = pack2(v[4], v[5]); o.w = pack2(v[6], v[7]);
            W2f[(size_t)(e * 256 + nt * 16 + kt) * 64 + l] = o;
        }
        return;
    }
    if (bx >= ROUTER_BLOCKS) {
        // ------ W1 prep (v16-verified strided form) -------------------------
        int g = (bx - ROUTER_BLOCKS) * 256 + tid;   // 0 .. 2^20-1
        int l = g & 63;
        int t = g >> 6;            // tile id over all experts
        int e = t >> 8;
        int rem = t & 255;
        int quad = l >> 4, lr = l & 15;
        int nt = rem >> 3, kt = rem & 7;            // 32 n-tiles, 8 k-tiles
        int kb = kt * 32 + quad * 8;
        int n = nt * 16 + lr;
        const float* s = W1 + (size_t)e * DIN * DHID + n;
        float v[8];
#pragma unroll
        for (int j = 0; j < 8; ++j) v[j] = s[(size_t)(kb + j) * DHID];
        uint4 o;
        o.x = pack2(v[0], v[1]); o.y = pack2(v[2], v[3]);
        o.z = pack2(v[4], v[5]); o.w = pack2(v[6], v[7]);
        W1f[g] = o;
        return;
    }

    // ---------------- router (v17-verified ldsf-aliased form) --------------
    float (*xl)[68] = (float(*)[68])ldsf;                 // [64][68]
    float (*wt)[68] = (float(*)[68])(ldsf + 64 * 68);     // [64][68]
    if (tid < NEXP) lcnt[tid] = 0;
    int a = tid >> 4;        // expert group base
    int bcol = tid & 15;     // token group base
    int tok0 = bx * 64;
    float c[4][4];
#pragma unroll
    for (int i = 0; i < 4; ++i)
#pragma unroll
        for (int j = 0; j < 4; ++j) c[i][j] = 0.0f;

    for (int chunk = 0; chunk < 4; ++chunk) {
        int d0 = chunk * 64;
        {   // stage x[tok0..tok0+63][d0..d0+63]
            int tok = tid >> 2, off = (tid & 3) * 16;
            const float4* s = (const float4*)(x + (size_t)(tok0 + tok) * DIN + d0 + off);
            float4* d = (float4*)&xl[tok][off];
#pragma unroll
            for (int i = 0; i < 4; ++i) d[i] = s[i];
        }
        {   // stage Wr chunk transposed: wt[e][dd] = Wr[d0+dd][e]
            int dd = tid >> 2, ecol = (tid & 3) * 16;
            const float* s = Wr + (size_t)(d0 + dd) * NEXP + ecol;
#pragma unroll
            for (int j = 0; j < 16; ++j) wt[ecol + j][dd] = s[j];
        }
        __syncthreads();
#pragma unroll 4
        for (int d = 0; d < 64; d += 4) {
            float4 xv[4], wv[4];
#pragma unroll
            for (int i = 0; i < 4; ++i) xv[i] = *(const float4*)&xl[bcol + i * 16][d];
#pragma unroll
            for (int j = 0; j < 4; ++j) wv[j] = *(const float4*)&wt[a + j * 16][d];
#pragma unroll
            for (int i = 0; i < 4; ++i)
#pragma unroll
                for (int j = 0; j < 4; ++j) {
                    c[i][j] = fmaf(xv[i].x, wv[j].x, c[i][j]);
                    c[i][j] = fmaf(xv[i].y, wv[j].y, c[i][j]);
                    c[i][j] = fmaf(xv[i].z, wv[j].z, c[i][j]);
                    c[i][j] = fmaf(xv[i].w, wv[j].w, c[i][j]);
                }
        }
        __syncthreads();
    }
#pragma unroll
    for (int i = 0; i < 4; ++i)
#pragma unroll
        for (int j = 0; j < 4; ++j)
            xl[bcol + i * 16][a + j * 16] = c[i][j] + br[a + j * 16];
    __syncthreads();

    int w = tid >> 6, lane = tid & 63;
    for (int ti = 0; ti < 16; ++ti) {
        int tl = w * 16 + ti;
        float acc = xl[tl][lane];     // lane == expert
        float v = acc; int idx = lane;
#pragma unroll
        for (int m = 32; m; m >>= 1) {
            float ov = __shfl_xor(v, m); int oi = __shfl_xor(idx, m);
            if (ov > v || (ov == v && oi < idx)) { v = ov; idx = oi; }
        }
        int e0 = idx; float l0 = v;
        float v2 = (lane == e0) ? -3.4e38f : acc; int idx2 = lane;
#pragma unroll
        for (int m = 32; m; m >>= 1) {
            float ov = __shfl_xor(v2, m); int oi = __shfl_xor(idx2, m);
            if (ov > v2 || (ov == v2 && oi < idx2)) { v2 = ov; idx2 = oi; }
        }
        if (lane == 0) {
            int t = tok0 + tl;
            float ex = expf(v2 - l0);         // <= 1
            float g1 = ex / (1.0f + ex);
            topk_e[2 * t] = e0; topk_e[2 * t + 1] = idx2;
            topk_g[2 * t] = 1.0f - g1; topk_g[2 * t + 1] = g1;
            atomicAdd(&lcnt[e0], 1);
            atomicAdd(&lcnt[idx2], 1);
        }
    }
    __syncthreads();
    if (tid < NEXP) atomicAdd(&cnt[tid], lcnt[tid]);
}

// ---------------------------------------------------------------------------
// K2: scatter; wave 0 also scans cnt. Block 0 publishes offs (token-slot
// prefix). Also records islot[2t], islot[2t+1] = token t's perm slots, for
// the gather-combine kernel.
__global__ __launch_bounds__(256) void scatter_kernel(const int* __restrict__ topk_e,
                                                      const float* __restrict__ topk_g,
                                                      const int* __restrict__ cnt,
                                                      int* __restrict__ cursor,
                                                      int* __restrict__ perm,
                                                      int* __restrict__ islot,
                                                      int* __restrict__ offs_g) {
    __shared__ int lcnt[NEXP], lbase[NEXP], sOffs[NEXP];
    int tid = threadIdx.x;
    if (tid < NEXP) lcnt[tid] = 0;
    if (tid < 64) {   // wave 0
        int c = cnt[tid];
        int ic = c;
#pragma unroll
        for (int d = 1; d < 64; d <<= 1) {
            int vc = __shfl_up(ic, d);
            if (tid >= d) ic += vc;
        }
        sOffs[tid] = ic - c;
        if (blockIdx.x == 0) {
            offs_g[tid] = ic - c;
            if (tid == 63) offs_g[64] = ic;
        }
    }
    __syncthreads();
    int t = blockIdx.x * 256 + tid;
    int e0 = topk_e[2 * t], e1 = topk_e[2 * t + 1];
    int i0 = atomicAdd(&lcnt[e0], 1);
    int i1 = atomicAdd(&lcnt[e1], 1);
    __syncthreads();
    if (tid < NEXP) lbase[tid] = atomicAdd(&cursor[tid], lcnt[tid]);
    __syncthreads();
    int p0 = sOffs[e0] + lbase[e0] + i0;
    int p1 = sOffs[e1] + lbase[e1] + i1;
    perm[p0] = t;
    perm[p1] = t;
    islot[2 * t] = p0;
    islot[2 * t + 1] = p1;
}

// ---------------------------------------------------------------------------
// Expert FFN (v16 champion form, unchanged): expert-stationary with T1
// XCD-affinity swizzle; l1 512-thr one-64KB-strip; l2 256-thr two-k-halves;
// atomic-free yp epilogue + combine.
//
// expert_l1: block = (expert e, n-strip ns of DHID/128, slot). W1 strip
// (256k x 128n bf16 = 64 KB) staged in LDS ONCE; loop 256-token chunks.
// MFMA 16x16x32 bf16: A[m=lane&15][k=(lane>>4)*8+j]; C/D col=lane&15,
// row=(lane>>4)*4+reg.
__global__ __launch_bounds__(512, 4) void expert_l1(const unsigned short* __restrict__ xbf,
                                                    const uint4* __restrict__ W1f,
                                                    const float* __restrict__ b1,
                                                    const int* __restrict__ cnt,
                                                    const int* __restrict__ offs,
                                                    const int* __restrict__ perm,
                                                    unsigned short* __restrict__ H) {
    __shared__ uint4 Wlds[4096];   // 64 KB: [(i*8+kt)*64 + lane], i = nt within strip
    __shared__ int toks[256];
    __shared__ float b1s[128];

    int tid = threadIdx.x;
    int e, j;
    xcd_decode(blockIdx.x, e, j);
    int ns = j & 3, slot = j >> 2;
    int ne = cnt[e];
    if (slot * 256 >= ne) return;
    int base = offs[e];
    int w = tid >> 6, lane = tid & 63, quad = lane >> 4, lr = lane & 15;

    // stage W1 strip once: 64 contiguous fragment-tiles (nt in [ns*8, ns*8+8))
    // LDS dest wave-uniform (+w*64); HW adds lane*16B; src per-lane.
    const uint4* src = W1f + (size_t)(e * 256 + ns * 64) * 64;
#pragma unroll
    for (int r = 0; r < 8; ++r)
        async_copy16(src + r * 512 + w * 64 + lane, Wlds + r * 512 + w * 64);
    if (tid < 32)
        *(float4*)&b1s[tid * 4] =
            *(const float4*)(b1 + (size_t)e * DHID + ns * 128 + tid * 4);

    for (int mc = slot; mc * 256 < ne; mc += L1_SLOTS) {
        __syncthreads();   // prev chunk's toks reads done; 1st iter: DMA drain
        if (tid < 256) {
            int idx = mc * 256 + tid;
            toks[tid] = perm[base + (idx < ne ? idx : ne - 1)];
        }
        __syncthreads();   // toks visible

        // A-frags: wave w owns m-tiles 2w, 2w+1 (of 16); batch-issued
        short8 a[2][8];
#pragma unroll
        for (int mt = 0; mt < 2; ++mt) {
            const unsigned short* xr =
                xbf + (size_t)toks[(w * 2 + mt) * 16 + lr] * DIN + quad * 8;
#pragma unroll
            for (int kt = 0; kt < 8; ++kt) a[mt][kt] = *(const short8*)(xr + kt * 32);
        }

#pragma unroll
        for (int ntb = 0; ntb < 4; ++ntb) {
            f32x4 acc[2][2];   // [nt2][mt]
#pragma unroll
            for (int i = 0; i < 2; ++i)
#pragma unroll
                for (int m = 0; m < 2; ++m) acc[i][m] = (f32x4){0.f, 0.f, 0.f, 0.f};
#pragma unroll
            for (int kt = 0; kt < 8; ++kt) {
                short8 B0 = *(const short8*)&Wlds[((ntb * 2 + 0) * 8 + kt) * 64 + lane];
                short8 B1 = *(const short8*)&Wlds[((ntb * 2 + 1) * 8 + kt) * 64 + lane];
#pragma unroll
                for (int mt = 0; mt < 2; ++mt) {
                    acc[0][mt] = __builtin_amdgcn_mfma_f32_16x16x32_bf16(a[mt][kt], B0, acc[0][mt], 0, 0, 0);
                    acc[1][mt] = __builtin_amdgcn_mfma_f32_16x16x32_bf16(a[mt][kt], B1, acc[1][mt], 0, 0, 0);
                }
            }
#pragma unroll
            for (int nt2 = 0; nt2 < 2; ++nt2) {
                int nloc = ntb * 32 + nt2 * 16 + lr;
                float bias = b1s[nloc];
#pragma unroll
                for (int mt = 0; mt < 2; ++mt)
#pragma unroll
                    for (int r = 0; r < 4; ++r) {
                        int idx = mc * 256 + (w * 2 + mt) * 16 + quad * 4 + r;
                        if (idx < ne)
                            H[(size_t)(base + idx) * DHID + ns * 128 + nloc] =
                                f2bf(fmaxf(acc[nt2][mt][r] + bias, 0.0f));
                    }
            }
        }
    }
}

// ---------------------------------------------------------------------------
// expert_l2 (v13 proven form + swizzle): block = (expert, out-strip ns,
// slot), 256 thr; loops 128-token chunks. W2 strip staged per chunk in two
// 64 KB k-halves. Atomic-free: stores y+b2 (bf16) to perm-ordered yp.
__global__ __launch_bounds__(256, 2) void expert_l2(const unsigned short* __restrict__ H,
                                                    const uint4* __restrict__ W2f,
                                                    const float* __restrict__ b2,
                                                    const int* __restrict__ cnt,
                                                    const int* __restrict__ offs,
                                                    unsigned short* __restrict__ yp) {
    __shared__ uint4 Wlds[4096];   // 64 KB: [(nt*8 + ktl)*64 + lane]
    __shared__ float b2s[128];

    int tid = threadIdx.x;
    int e, j;
    xcd_decode(blockIdx.x, e, j);
    int ns = j & 1, slot = j >> 1;
    int ne = cnt[e];
    if (slot * 128 >= ne) return;
    int base = offs[e];
    int w = tid >> 6, lane = tid & 63, quad = lane >> 4, lr = lane & 15;

    if (tid < 32)
        *(float4*)&b2s[tid * 4] =
            *(const float4*)(b2 + (size_t)e * DOUT + ns * 128 + tid * 4);

    for (int mc = slot; mc * 128 < ne; mc += L2_SLOTS) {
        int row0 = mc * 128 + (w * 2 + 0) * 16 + lr;
        int row1 = mc * 128 + (w * 2 + 1) * 16 + lr;
        if (row0 >= ne) row0 = ne - 1;
        if (row1 >= ne) row1 = ne - 1;
        const unsigned short* h0 = H + (size_t)(base + row0) * DHID + quad * 8;
        const unsigned short* h1 = H + (size_t)(base + row1) * DHID + quad * 8;

        f32x4 acc[8][2];   // [nt][mt]
#pragma unroll
        for (int nt = 0; nt < 8; ++nt)
#pragma unroll
            for (int mt = 0; mt < 2; ++mt) acc[nt][mt] = (f32x4){0.f, 0.f, 0.f, 0.f};

#pragma unroll
        for (int kh = 0; kh < 2; ++kh) {
            __syncthreads();   // prev phase done reading Wlds
            // stage k-half: per nt, 512 contiguous uint4 (8 k-tiles)
#pragma unroll
            for (int nt = 0; nt < 8; ++nt) {
                const uint4* src = W2f + (size_t)(e * 256 + (ns * 8 + nt) * 16 + kh * 8) * 64;
                async_copy16(src + w * 64 + lane, Wlds + nt * 512 + w * 64);
                async_copy16(src + 256 + w * 64 + lane, Wlds + nt * 512 + 256 + w * 64);
            }
            __syncthreads();   // DMA drained

            // batch-issue all A-frags for this k-half
            short8 a[8][2];
#pragma unroll
            for (int kt = 0; kt < 8; ++kt) {
                a[kt][0] = *(const short8*)(h0 + kh * 256 + kt * 32);
                a[kt][1] = *(const short8*)(h1 + kh * 256 + kt * 32);
            }
#pragma unroll
            for (int kt = 0; kt < 8; ++kt) {
#pragma unroll
                for (int nt = 0; nt < 8; ++nt) {
                    short8 B = *(const short8*)&Wlds[(nt * 8 + kt) * 64 + lane];
                    acc[nt][0] = __builtin_amdgcn_mfma_f32_16x16x32_bf16(a[kt][0], B, acc[nt][0], 0, 0, 0);
                    acc[nt][1] = __builtin_amdgcn_mfma_f32_16x16x32_bf16(a[kt][1], B, acc[nt][1], 0, 0, 0);
                }
            }
        }

        // ---- epilogue: yp[slot] = y + b2 (bf16), plain stores ----
#pragma unroll
        for (int nt = 0; nt < 8; ++nt) {
            int nloc = nt * 16 + lr;
            float bias = b2s[nloc];
#pragma unroll
            for (int mt = 0; mt < 2; ++mt)
#pragma unroll
                for (int r = 0; r < 4; ++r) {
                    int crow = mc * 128 + (w * 2 + mt) * 16 + quad * 4 + r;
                    if (crow < ne)
                        yp[(size_t)(base + crow) * DOUT + ns * 128 + nloc] =
                            f2bf(acc[nt][mt][r] + bias);
                }
        }
    }
}

// ---------------------------------------------------------------------------
// combine: out[t] = g0 * yp[p0] + g1 * yp[p1]. Pure streaming gather; 8
// tokens per 256-thr block, 32 lanes x 8 cols per token.
__global__ __launch_bounds__(256) void combine_out(const unsigned short* __restrict__ yp,
                                                   const int* __restrict__ islot,
                                                   const float* __restrict__ topk_g,
                                                   float* __restrict__ out) {
    int tid = threadIdx.x;
    int tok = blockIdx.x * 8 + (tid >> 5);
    int cseg = (tid & 31) * 8;
    int p0 = islot[2 * tok], p1 = islot[2 * tok + 1];
    float g0 = topk_g[2 * tok], g1 = topk_g[2 * tok + 1];
    short8 v0 = *(const short8*)(yp + (size_t)p0 * DOUT + cseg);
    short8 v1 = *(const short8*)(yp + (size_t)p1 * DOUT + cseg);
    float4 o0, o1;
    o0.x = g0 * bf2f((unsigned short)v0[0]) + g1 * bf2f((unsigned short)v1[0]);
    o0.y = g0 * bf2f((unsigned short)v0[1]) + g1 * bf2f((unsigned short)v1[1]);
    o0.z = g0 * bf2f((unsigned short)v0[2]) + g1 * bf2f((unsigned short)v1[2]);
    o0.w = g0 * bf2f((unsigned short)v0[3]) + g1 * bf2f((unsigned short)v1[3]);
    o1.x = g0 * bf2f((unsigned short)v0[4]) + g1 * bf2f((unsigned short)v1[4]);
    o1.y = g0 * bf2f((unsigned short)v0[5]) + g1 * bf2f((unsigned short)v1[5]);
    o1.z = g0 * bf2f((unsigned short)v0[6]) + g1 * bf2f((unsigned short)v1[6]);
    o1.w = g0 * bf2f((unsigned short)v0[7]) + g1 * bf2f((unsigned short)v1[7]);
    float* d = out + (size_t)tok * DOUT + cseg;
    *(float4*)d = o0;
    *(float4*)(d + 4) = o1;
}

// ---------------------------------------------------------------------------
extern "C" void kernel_launch(void* const* d_in, const int* in_sizes, int n_in,
                              void* d_out, int out_size, void* d_ws, size_t ws_size,
                              hipStream_t stream) {
    (void)in_sizes; (void)n_in; (void)ws_size; (void)out_size;   // ws >= ~146 MB
    const float* x  = (const float*)d_in[0];
    const float* Wr = (const float*)d_in[1];
    const float* br = (const float*)d_in[2];
    const float* W1 = (const float*)d_in[3];
    const float* b1 = (const float*)d_in[4];
    const float* W2 = (const float*)d_in[5];
    const float* b2 = (const float*)d_in[6];
    float* out = (float*)d_out;
    char* ws = (char*)d_ws;

    uint4*    W1f    = (uint4*)(ws + OFF_W1F);
    uint4*    W2f    = (uint4*)(ws + OFF_W2F);
    int*      cnt    = (int*)(ws + OFF_CNT);
    int*      cursor = (int*)(ws + OFF_CUR);
    int*      offs   = (int*)(ws + OFF_OFFS);
    int*      topk_e = (int*)(ws + OFF_TOPKE);
    float*    topk_g = (float*)(ws + OFF_TOPKG);
    int*      perm   = (int*)(ws + OFF_PERM);
    int*      islot  = (int*)(ws + OFF_ISLOT);
    unsigned* xbf    = (unsigned*)(ws + OFF_XBF);
    unsigned short* Hbuf = (unsigned short*)(ws + OFF_H);
    unsigned short* ypb  = (unsigned short*)(ws + OFF_YP);

    hipMemsetAsync(ws + OFF_CNT, 0, 512, stream);   // cnt + cursor

    router_prep<<<RP_TOTAL, 256, 0, stream>>>(
        x, Wr, br, W1, W2, W1f, W2f, topk_e, topk_g, cnt, xbf);
    scatter_kernel<<<T_TOK / 256, 256, 0, stream>>>(topk_e, topk_g, cnt, cursor,
                                                    perm, islot, offs);
    expert_l1<<<L1_BLOCKS, 512, 0, stream>>>((const unsigned short*)xbf, W1f, b1,
                                             cnt, offs, perm, Hbuf);
    expert_l2<<<L2_BLOCKS, 256, 0, stream>>>(Hbuf, W2f, b2, cnt, offs, ypb);
    combine_out<<<CMB_BLOCKS, 256, 0, stream>>>(ypb, islot, topk_g, out);
}